// Round 1
// baseline (5956.548 us; speedup 1.0000x reference)
//
#include <hip/hip_runtime.h>

#define NBATCH 16
#define NPTS   1024
#define NDIM   1024

typedef __attribute__((ext_vector_type(8))) short short8;
typedef __attribute__((ext_vector_type(4))) float f32x4;

__device__ __forceinline__ unsigned short f2bf(float f) {
  union { float f; unsigned u; } v; v.f = f;
  unsigned r = v.u + 0x7fffu + ((v.u >> 16) & 1u);
  return (unsigned short)(r >> 16);
}
__device__ __forceinline__ float bflo(unsigned x) { return __uint_as_float(x << 16); }
__device__ __forceinline__ float bfhi(unsigned x) { return __uint_as_float(x & 0xffff0000u); }

// ---------------- normalize: fp32 [B,N,D] -> unit rows, bf16 ----------------
__global__ __launch_bounds__(256) void norm_kernel(const float* __restrict__ x,
                                                   const float* __restrict__ y,
                                                   unsigned short* __restrict__ xf,
                                                   unsigned short* __restrict__ yf) {
  int row = blockIdx.x;
  const float* src; unsigned short* dst;
  if (row < NBATCH * NPTS) { src = x; dst = xf; }
  else { row -= NBATCH * NPTS; src = y; dst = yf; }
  src += (size_t)row * NDIM; dst += (size_t)row * NDIM;
  const int t = threadIdx.x;
  float4 val = ((const float4*)src)[t];
  float ss = val.x*val.x + val.y*val.y + val.z*val.z + val.w*val.w;
  #pragma unroll
  for (int o = 32; o; o >>= 1) ss += __shfl_xor(ss, o, 64);
  __shared__ float wsum[4];
  if ((t & 63) == 0) wsum[t >> 6] = ss;
  __syncthreads();
  float tot = wsum[0] + wsum[1] + wsum[2] + wsum[3];
  float inv = 1.0f / fmaxf(sqrtf(tot), 1e-12f);
  ushort4 o4;
  o4.x = f2bf(val.x * inv); o4.y = f2bf(val.y * inv);
  o4.z = f2bf(val.z * inv); o4.w = f2bf(val.w * inv);
  ((ushort4*)dst)[t] = o4;
}

// ---------------- batched bf16 GEMM: C[b] = 1 - A[b] * B[b]^T ----------------
// A,B row-major [NPTS][NDIM] bf16 per batch. 128x128 tile, 16x16x32 MFMA,
// global_load_lds width=16 staging (m97 structure).
#define GLD_LDS16(g, l) __builtin_amdgcn_global_load_lds( \
    (const __attribute__((address_space(1))) unsigned int*)(g), \
    (__attribute__((address_space(3))) unsigned int*)(l), 16, 0, 0)

__global__ __launch_bounds__(256) void gemm_cost(const unsigned short* __restrict__ A,
                                                 const unsigned short* __restrict__ B,
                                                 unsigned short* __restrict__ C,
                                                 unsigned* __restrict__ cmax_bits,
                                                 int domax) {
  const int b = blockIdx.z;
  const int bm = blockIdx.y * 128, bn = blockIdx.x * 128;
  const int t = threadIdx.x, lane = t & 63, wv = t >> 6;
  const int wm = (wv & 1) * 64, wn = (wv >> 1) * 64;
  __shared__ unsigned short As[128 * 32];
  __shared__ unsigned short Bs[128 * 32];
  f32x4 acc[4][4];
  #pragma unroll
  for (int i = 0; i < 4; ++i)
    #pragma unroll
    for (int j = 0; j < 4; ++j) acc[i][j] = (f32x4){0.f, 0.f, 0.f, 0.f};

  const unsigned short* gA = A + (size_t)b*NPTS*NDIM + (size_t)(bm + (t >> 2))*NDIM + (t & 3)*8;
  const unsigned short* gB = B + (size_t)b*NPTS*NDIM + (size_t)(bn + (t >> 2))*NDIM + (t & 3)*8;
  const int ar = lane & 15, ak = (lane >> 4) * 8;

  for (int k0 = 0; k0 < NDIM; k0 += 32) {
    // stage A tile (128 rows x 32 k): thread t -> LDS byte t*16 (+4096 for rows 64..127)
    GLD_LDS16(gA + k0,             As + t*8);
    GLD_LDS16(gA + 64*NDIM + k0,   As + 2048 + t*8);
    GLD_LDS16(gB + k0,             Bs + t*8);
    GLD_LDS16(gB + 64*NDIM + k0,   Bs + 2048 + t*8);
    __syncthreads();
    short8 af[4], bq[4];
    #pragma unroll
    for (int i = 0; i < 4; ++i) af[i] = *(const short8*)(As + (wm + i*16 + ar)*32 + ak);
    #pragma unroll
    for (int j = 0; j < 4; ++j) bq[j] = *(const short8*)(Bs + (wn + j*16 + ar)*32 + ak);
    #pragma unroll
    for (int i = 0; i < 4; ++i)
      #pragma unroll
      for (int j = 0; j < 4; ++j)
        acc[i][j] = __builtin_amdgcn_mfma_f32_16x16x32_bf16(af[i], bq[j], acc[i][j], 0, 0, 0);
    __syncthreads();
  }

  // epilogue: cost = 1 - dot ; C/D layout: col = lane&15, row = (lane>>4)*4 + reg
  float mx = 0.f;
  const int cr = (lane >> 4) * 4, cc = lane & 15;
  unsigned short* Cb = C + (size_t)b * NPTS * NPTS;
  #pragma unroll
  for (int i = 0; i < 4; ++i) {
    #pragma unroll
    for (int j = 0; j < 4; ++j) {
      const int row = bm + wm + i*16 + cr;
      const int col = bn + wn + j*16 + cc;
      unsigned short* cp = Cb + (size_t)row * NPTS + col;
      #pragma unroll
      for (int r = 0; r < 4; ++r) {
        float cv = 1.0f - acc[i][j][r];
        mx = fmaxf(mx, cv);
        cp[(size_t)r * NPTS] = f2bf(cv);
      }
    }
  }
  if (domax) {
    #pragma unroll
    for (int o = 32; o; o >>= 1) mx = fmaxf(mx, __shfl_xor(mx, o, 64));
    if (lane == 0) atomicMax(cmax_bits, __float_as_uint(mx));  // cost > 0 -> uint order == float order
  }
}

// ---------------- persistent Sinkhorn ----------------
__device__ __forceinline__ void batch_barrier(unsigned* bar, unsigned target) {
  __syncthreads();
  if (threadIdx.x == 0) {
    __threadfence();
    __hip_atomic_fetch_add(bar, 1u, __ATOMIC_RELAXED, __HIP_MEMORY_SCOPE_AGENT);
    while (__hip_atomic_load(bar, __ATOMIC_RELAXED, __HIP_MEMORY_SCOPE_AGENT) < target)
      __builtin_amdgcn_s_sleep(2);
    __threadfence();
  }
  __syncthreads();
}

__device__ __forceinline__ void load16(float* d, const float* __restrict__ src, int lane) {
  const float4* p4 = (const float4*)src + lane * 4;
  float4 a0 = p4[0], a1 = p4[1], a2 = p4[2], a3 = p4[3];
  d[0]=a0.x; d[1]=a0.y; d[2]=a0.z;  d[3]=a0.w;
  d[4]=a1.x; d[5]=a1.y; d[6]=a1.z;  d[7]=a1.w;
  d[8]=a2.x; d[9]=a2.y; d[10]=a2.z; d[11]=a2.w;
  d[12]=a3.x; d[13]=a3.y; d[14]=a3.z; d[15]=a3.w;
}

// full row (1024 bf16) dot with vr[16] per lane (lane covers m = lane*16..+15)
__device__ __forceinline__ float rowdot(const unsigned short* __restrict__ Mrow,
                                        const float* vr, int lane) {
  const uint4* rp = (const uint4*)(Mrow + lane * 16);
  uint4 p0 = rp[0], p1 = rp[1];
  float s = 0.f;
  s += bflo(p0.x)*vr[0]  + bfhi(p0.x)*vr[1];
  s += bflo(p0.y)*vr[2]  + bfhi(p0.y)*vr[3];
  s += bflo(p0.z)*vr[4]  + bfhi(p0.z)*vr[5];
  s += bflo(p0.w)*vr[6]  + bfhi(p0.w)*vr[7];
  s += bflo(p1.x)*vr[8]  + bfhi(p1.x)*vr[9];
  s += bflo(p1.y)*vr[10] + bfhi(p1.y)*vr[11];
  s += bflo(p1.z)*vr[12] + bfhi(p1.z)*vr[13];
  s += bflo(p1.w)*vr[14] + bfhi(p1.w)*vr[15];
  #pragma unroll
  for (int o = 32; o; o >>= 1) s += __shfl_xor(s, o, 64);
  return s;
}

__global__ __launch_bounds__(256) void sinkhorn_kernel(
    const unsigned short* __restrict__ Cmat, const unsigned short* __restrict__ CTmat,
    float* __restrict__ u, float* __restrict__ v,
    unsigned* __restrict__ bar, float* __restrict__ dist,
    const unsigned* __restrict__ cmax_bits) {
  const int wg = blockIdx.x;
  const int b = wg & (NBATCH - 1);   // batch = wg%16 -> 16 WGs/batch, XCD-local if %8 round-robin
  const int slice = wg >> 4;         // 0..15: owns rows/cols [slice*64, slice*64+64)
  const int t = threadIdx.x, lane = t & 63, wv = t >> 6;
  const int n0 = slice * 64 + wv * 16;  // this wave's 16 rows
  const float inv_cmax = 1.0f / __uint_as_float(*cmax_bits);
  const float EPSI = 1e-3f;
  float* ub = u + b * NPTS;
  float* vb = v + b * NPTS;
  const unsigned short* Cb  = Cmat  + (size_t)b * NPTS * NPTS;
  const unsigned short* CTb = CTmat + (size_t)b * NPTS * NPTS;
  unsigned* barb = bar + b;

  if (wv == 0) vb[slice * 64 + lane] = 1.0f / (float)NPTS;   // v0 = 1/n (u0 never read)
  unsigned bt = 16;
  batch_barrier(barb, bt);

  float ulocal[16];
  float vr[16];
  for (int it = 0; it < 100; ++it) {
    // u = 1 / ((C~ v) * inv_cmax + eps)
    load16(vr, vb, lane);
    #pragma unroll 4
    for (int r = 0; r < 16; ++r) {
      const int n = n0 + r;
      float s = rowdot(Cb + (size_t)n * NPTS, vr, lane);
      if (lane == 0) {
        float uu = 1.0f / (s * inv_cmax + EPSI);
        ulocal[r] = uu;
        ub[n] = uu;
      }
    }
    bt += 16; batch_barrier(barb, bt);
    // v = 1 / ((C~^T u) * inv_cmax + eps)
    load16(vr, ub, lane);
    #pragma unroll 4
    for (int r = 0; r < 16; ++r) {
      const int m = n0 + r;
      float s = rowdot(CTb + (size_t)m * NPTS, vr, lane);
      if (lane == 0) vb[m] = 1.0f / (s * inv_cmax + EPSI);
    }
    bt += 16; batch_barrier(barb, bt);
  }

  // distance_b = sum_n u_n * (C v)_n * inv_cmax
  load16(vr, vb, lane);
  float part = 0.f;
  #pragma unroll 4
  for (int r = 0; r < 16; ++r) {
    const int n = n0 + r;
    float s = rowdot(Cb + (size_t)n * NPTS, vr, lane);
    if (lane == 0) part += ulocal[r] * (s * inv_cmax);
  }
  if (lane == 0) atomicAdd(dist + b, part);
}

__global__ void finalize_kernel(const float* __restrict__ dist, float* __restrict__ out) {
  if (threadIdx.x == 0) {
    float s = 0.f;
    for (int i = 0; i < NBATCH; ++i) s += dist[i];
    out[0] = s * (1.0f / NBATCH);
  }
}

// ---------------- launch ----------------
extern "C" void kernel_launch(void* const* d_in, const int* in_sizes, int n_in,
                              void* d_out, int out_size, void* d_ws, size_t ws_size,
                              hipStream_t stream) {
  (void)in_sizes; (void)n_in; (void)out_size; (void)ws_size;
  const float* x = (const float*)d_in[0];
  const float* y = (const float*)d_in[1];
  float* out = (float*)d_out;
  char* ws = (char*)d_ws;

  // workspace layout (bytes): needs ~129 MB
  unsigned* cmax_bits = (unsigned*)ws;            // [0,4)
  unsigned* bar       = (unsigned*)(ws + 64);     // 16 counters
  float*    dist      = (float*)(ws + 256);       // 16 floats
  float*    u         = (float*)(ws + 4096);                 // 64 KB
  float*    v         = (float*)(ws + 4096 + 65536);         // 64 KB
  const size_t MB = 1u << 20;
  unsigned short* xf = (unsigned short*)(ws + 1*MB);          // 32 MB
  unsigned short* yf = (unsigned short*)(ws + 33*MB);         // 32 MB
  unsigned short* C  = (unsigned short*)(ws + 65*MB);         // 32 MB
  unsigned short* CT = (unsigned short*)(ws + 97*MB);         // 32 MB

  hipMemsetAsync(d_ws, 0, 4096, stream);  // zero cmax / barriers / dist

  hipLaunchKernelGGL(norm_kernel, dim3(2 * NBATCH * NPTS), dim3(256), 0, stream, x, y, xf, yf);
  hipLaunchKernelGGL(gemm_cost, dim3(8, 8, NBATCH), dim3(256), 0, stream, xf, yf, C,  cmax_bits, 1);
  hipLaunchKernelGGL(gemm_cost, dim3(8, 8, NBATCH), dim3(256), 0, stream, yf, xf, CT, cmax_bits, 0);
  hipLaunchKernelGGL(sinkhorn_kernel, dim3(256), dim3(256), 0, stream, C, CT, u, v, bar, dist, cmax_bits);
  hipLaunchKernelGGL(finalize_kernel, dim3(1), dim3(64), 0, stream, dist, out);
}

// Round 2
// 2668.095 us; speedup vs baseline: 2.2325x; 2.2325x over previous
//
#include <hip/hip_runtime.h>

#define NBATCH 16
#define NPTS   1024
#define NDIM   1024
#define EPSI   1e-3f
#define NWAVES 8

typedef __attribute__((ext_vector_type(8))) short short8;
typedef __attribute__((ext_vector_type(4))) float f32x4;

__device__ __forceinline__ unsigned short f2bf(float f) {
  union { float f; unsigned u; } v; v.f = f;
  unsigned r = v.u + 0x7fffu + ((v.u >> 16) & 1u);
  return (unsigned short)(r >> 16);
}
__device__ __forceinline__ float bflo(unsigned x) { return __uint_as_float(x << 16); }
__device__ __forceinline__ float bfhi(unsigned x) { return __uint_as_float(x & 0xffff0000u); }

// device-coherent scalar access (per-access sc bits; NO cache-wide fences)
__device__ __forceinline__ float ld_agent(const float* p) {
  return __hip_atomic_load(p, __ATOMIC_RELAXED, __HIP_MEMORY_SCOPE_AGENT);
}
__device__ __forceinline__ void st_agent(float* p, float v) {
  __hip_atomic_store(p, v, __ATOMIC_RELAXED, __HIP_MEMORY_SCOPE_AGENT);
}

// ---------------- normalize: fp32 [B,N,D] -> unit rows, bf16 ----------------
__global__ __launch_bounds__(256) void norm_kernel(const float* __restrict__ x,
                                                   const float* __restrict__ y,
                                                   unsigned short* __restrict__ xf,
                                                   unsigned short* __restrict__ yf) {
  int row = blockIdx.x;
  const float* src; unsigned short* dst;
  if (row < NBATCH * NPTS) { src = x; dst = xf; }
  else { row -= NBATCH * NPTS; src = y; dst = yf; }
  src += (size_t)row * NDIM; dst += (size_t)row * NDIM;
  const int t = threadIdx.x;
  float4 val = ((const float4*)src)[t];
  float ss = val.x*val.x + val.y*val.y + val.z*val.z + val.w*val.w;
  #pragma unroll
  for (int o = 32; o; o >>= 1) ss += __shfl_xor(ss, o, 64);
  __shared__ float wsum[4];
  if ((t & 63) == 0) wsum[t >> 6] = ss;
  __syncthreads();
  float tot = wsum[0] + wsum[1] + wsum[2] + wsum[3];
  float inv = 1.0f / fmaxf(sqrtf(tot), 1e-12f);
  ushort4 o4;
  o4.x = f2bf(val.x * inv); o4.y = f2bf(val.y * inv);
  o4.z = f2bf(val.z * inv); o4.w = f2bf(val.w * inv);
  ((ushort4*)dst)[t] = o4;
}

// ---------------- batched bf16 GEMM: C[b] = 1 - A[b] * B[b]^T ----------------
#define GLD_LDS16(g, l) __builtin_amdgcn_global_load_lds( \
    (const __attribute__((address_space(1))) unsigned int*)(g), \
    (__attribute__((address_space(3))) unsigned int*)(l), 16, 0, 0)

__global__ __launch_bounds__(256) void gemm_cost(const unsigned short* __restrict__ A,
                                                 const unsigned short* __restrict__ B,
                                                 unsigned short* __restrict__ C,
                                                 unsigned* __restrict__ cmax_bits,
                                                 int domax) {
  const int b = blockIdx.z;
  const int bm = blockIdx.y * 128, bn = blockIdx.x * 128;
  const int t = threadIdx.x, lane = t & 63, wv = t >> 6;
  const int wm = (wv & 1) * 64, wn = (wv >> 1) * 64;
  __shared__ unsigned short As[128 * 32];
  __shared__ unsigned short Bs[128 * 32];
  f32x4 acc[4][4];
  #pragma unroll
  for (int i = 0; i < 4; ++i)
    #pragma unroll
    for (int j = 0; j < 4; ++j) acc[i][j] = (f32x4){0.f, 0.f, 0.f, 0.f};

  const unsigned short* gA = A + (size_t)b*NPTS*NDIM + (size_t)(bm + (t >> 2))*NDIM + (t & 3)*8;
  const unsigned short* gB = B + (size_t)b*NPTS*NDIM + (size_t)(bn + (t >> 2))*NDIM + (t & 3)*8;
  const int ar = lane & 15, ak = (lane >> 4) * 8;

  for (int k0 = 0; k0 < NDIM; k0 += 32) {
    GLD_LDS16(gA + k0,             As + t*8);
    GLD_LDS16(gA + 64*NDIM + k0,   As + 2048 + t*8);
    GLD_LDS16(gB + k0,             Bs + t*8);
    GLD_LDS16(gB + 64*NDIM + k0,   Bs + 2048 + t*8);
    __syncthreads();
    short8 af[4], bq[4];
    #pragma unroll
    for (int i = 0; i < 4; ++i) af[i] = *(const short8*)(As + (wm + i*16 + ar)*32 + ak);
    #pragma unroll
    for (int j = 0; j < 4; ++j) bq[j] = *(const short8*)(Bs + (wn + j*16 + ar)*32 + ak);
    #pragma unroll
    for (int i = 0; i < 4; ++i)
      #pragma unroll
      for (int j = 0; j < 4; ++j)
        acc[i][j] = __builtin_amdgcn_mfma_f32_16x16x32_bf16(af[i], bq[j], acc[i][j], 0, 0, 0);
    __syncthreads();
  }

  float mx = 0.f;
  const int cr = (lane >> 4) * 4, cc = lane & 15;
  unsigned short* Cb = C + (size_t)b * NPTS * NPTS;
  #pragma unroll
  for (int i = 0; i < 4; ++i) {
    #pragma unroll
    for (int j = 0; j < 4; ++j) {
      const int row = bm + wm + i*16 + cr;
      const int col = bn + wn + j*16 + cc;
      unsigned short* cp = Cb + (size_t)row * NPTS + col;
      #pragma unroll
      for (int r = 0; r < 4; ++r) {
        float cv = 1.0f - acc[i][j][r];
        mx = fmaxf(mx, cv);
        cp[(size_t)r * NPTS] = f2bf(cv);
      }
    }
  }
  if (domax) {
    #pragma unroll
    for (int o = 32; o; o >>= 1) mx = fmaxf(mx, __shfl_xor(mx, o, 64));
    if (lane == 0) atomicMax(cmax_bits, __float_as_uint(mx));
  }
}

// ---------------- persistent Sinkhorn ----------------
// 256 WGs x 512 thr. WG = (batch b, s); s -> out-slice a (256 outputs),
// red-chunk j (256 reduction idx). Phase U: out=n over CT; phase V: out=m over C.
// Partials: part[idx][4] (one slot per red-chunk WG); consumer sums 4 + transform.
// Barrier: per-batch counter, 256B-spaced, RELEASE arrive + RELAXED spin. No fences.

__device__ __forceinline__ void batch_barrier(unsigned* bar, unsigned target) {
  __syncthreads();
  if (threadIdx.x == 0) {
    __hip_atomic_fetch_add(bar, 1u, __ATOMIC_RELEASE, __HIP_MEMORY_SCOPE_AGENT);
    while (__hip_atomic_load(bar, __ATOMIC_RELAXED, __HIP_MEMORY_SCOPE_AGENT) < target)
      __builtin_amdgcn_s_sleep(4);
    asm volatile("" ::: "memory");
  }
  __syncthreads();
}

__device__ __forceinline__ void half_step(
    const unsigned short* __restrict__ M,   // per-batch matrix (rows = reduction idx)
    const float* __restrict__ srcp,         // src partials [1024][4]
    float* __restrict__ dstp,               // dst partials [1024][4] (unused if distance)
    const float* __restrict__ ufac,         // u partials (distance pass only)
    float* __restrict__ distb,              // null unless distance pass
    int ob, int rb, int j, float invc,
    int lane, int w, int tid,
    float* gbuf, float (*red)[256], float* dred)
{
  // stage transformed source values for this wave's 32 reduction indices
  if (lane < 32) {
    int m = rb + w * 32 + lane;
    float sum = ld_agent(&srcp[m * 4 + 0]) + ld_agent(&srcp[m * 4 + 1])
              + ld_agent(&srcp[m * 4 + 2]) + ld_agent(&srcp[m * 4 + 3]);
    gbuf[w * 32 + lane] = 1.0f / (sum * invc + EPSI);
  }
  float acc0 = 0.f, acc1 = 0.f, acc2 = 0.f, acc3 = 0.f;
  const unsigned short* rowp = M + (size_t)(rb + w * 32) * NPTS + ob + lane * 4;
  #pragma unroll 8
  for (int mi = 0; mi < 32; ++mi) {
    uint2 cc = *(const uint2*)(rowp + (size_t)mi * NPTS);
    float g = gbuf[w * 32 + mi];
    acc0 += bflo(cc.x) * g;
    acc1 += bfhi(cc.x) * g;
    acc2 += bflo(cc.y) * g;
    acc3 += bfhi(cc.y) * g;
  }
  ((float4*)&red[w][lane * 4])[0] = make_float4(acc0, acc1, acc2, acc3);
  __syncthreads();
  if (distb == nullptr) {
    if (tid < 256) {
      float ssum = 0.f;
      #pragma unroll
      for (int ww = 0; ww < NWAVES; ++ww) ssum += red[ww][tid];
      st_agent(&dstp[(ob + tid) * 4 + j], ssum);
    }
  } else {
    float term = 0.f;
    if (tid < 256) {
      float ssum = 0.f;
      #pragma unroll
      for (int ww = 0; ww < NWAVES; ++ww) ssum += red[ww][tid];
      int n = ob + tid;
      float uq = ld_agent(&ufac[n * 4 + 0]) + ld_agent(&ufac[n * 4 + 1])
               + ld_agent(&ufac[n * 4 + 2]) + ld_agent(&ufac[n * 4 + 3]);
      float un = 1.0f / (uq * invc + EPSI);
      term = un * ssum * invc;
    }
    #pragma unroll
    for (int o = 32; o; o >>= 1) term += __shfl_xor(term, o, 64);
    if (lane == 0) dred[w] = term;
    __syncthreads();
    if (tid == 0) {
      float d = 0.f;
      #pragma unroll
      for (int ww = 0; ww < NWAVES; ++ww) d += dred[ww];
      atomicAdd(distb, d);
    }
  }
}

__global__ __launch_bounds__(512) void sinkhorn_kernel(
    const unsigned short* __restrict__ Cmat, const unsigned short* __restrict__ CTmat,
    float* __restrict__ u_part, float* __restrict__ v_part,
    unsigned* __restrict__ bar, float* __restrict__ dist,
    const unsigned* __restrict__ cmax_bits)
{
  const int wg = blockIdx.x;
  const int b = wg & (NBATCH - 1);
  const int s = wg >> 4;              // 0..15
  const int a = s & 3, j = s >> 2;    // out-slice / red-chunk
  const int ob = a * 256, rb = j * 256;
  const int tid = threadIdx.x, lane = tid & 63, w = tid >> 6;

  __shared__ float gbuf[256];
  __shared__ float red[NWAVES][256];
  __shared__ float dred[NWAVES];

  const float cmax = __uint_as_float(*cmax_bits);
  const float invc = 1.0f / cmax;
  const unsigned short* Cb  = Cmat  + (size_t)b * NPTS * NPTS;
  const unsigned short* CTb = CTmat + (size_t)b * NPTS * NPTS;
  float* up = u_part + b * NPTS * 4;
  float* vp = v_part + b * NPTS * 4;
  unsigned* barb = bar + b * 64;      // 256-byte spacing: no false sharing

  // init v_part rows [s*64, s*64+64): f_v(sum) == 1/N
  if (tid < 64) {
    float iv = cmax * ((float)NPTS - EPSI) * 0.25f;
    #pragma unroll
    for (int k = 0; k < 4; ++k) st_agent(&vp[(s * 64 + tid) * 4 + k], iv);
  }
  unsigned bt = 16;
  batch_barrier(barb, bt); bt += 16;

  for (int it = 0; it < 100; ++it) {
    // u_raw = CT-rows dot f(v_raw)
    half_step(CTb, vp, up, nullptr, nullptr, ob, rb, j, invc, lane, w, tid, gbuf, red, dred);
    batch_barrier(barb, bt); bt += 16;
    // v_raw = C-rows dot f(u_raw)
    half_step(Cb, up, vp, nullptr, nullptr, ob, rb, j, invc, lane, w, tid, gbuf, red, dred);
    batch_barrier(barb, bt); bt += 16;
  }
  // distance: sum_n f(u_raw[n]) * (C~ v)_n
  half_step(CTb, vp, nullptr, up, dist + b, ob, rb, j, invc, lane, w, tid, gbuf, red, dred);
}

__global__ void finalize_kernel(const float* __restrict__ dist, float* __restrict__ out) {
  if (threadIdx.x == 0) {
    float s = 0.f;
    for (int i = 0; i < NBATCH; ++i) s += dist[i];
    out[0] = s * (1.0f / NBATCH);
  }
}

// ---------------- launch ----------------
extern "C" void kernel_launch(void* const* d_in, const int* in_sizes, int n_in,
                              void* d_out, int out_size, void* d_ws, size_t ws_size,
                              hipStream_t stream) {
  (void)in_sizes; (void)n_in; (void)out_size; (void)ws_size;
  const float* x = (const float*)d_in[0];
  const float* y = (const float*)d_in[1];
  float* out = (float*)d_out;
  char* ws = (char*)d_ws;

  unsigned* cmax_bits = (unsigned*)ws;                 // @0
  unsigned* bar       = (unsigned*)(ws + 4096);        // 16 x 256B
  float*    dist      = (float*)(ws + 8192);           // 16 floats
  float*    u_part    = (float*)(ws + 65536);          // 256 KB
  float*    v_part    = (float*)(ws + 65536 + 262144); // 256 KB
  const size_t MB = 1u << 20;
  unsigned short* xf = (unsigned short*)(ws + 1*MB);   // 32 MB
  unsigned short* yf = (unsigned short*)(ws + 33*MB);  // 32 MB
  unsigned short* C  = (unsigned short*)(ws + 65*MB);  // 32 MB
  unsigned short* CT = (unsigned short*)(ws + 97*MB);  // 32 MB

  hipMemsetAsync(d_ws, 0, 65536, stream);  // cmax / barriers / dist

  hipLaunchKernelGGL(norm_kernel, dim3(2 * NBATCH * NPTS), dim3(256), 0, stream, x, y, xf, yf);
  hipLaunchKernelGGL(gemm_cost, dim3(8, 8, NBATCH), dim3(256), 0, stream, xf, yf, C,  cmax_bits, 1);
  hipLaunchKernelGGL(gemm_cost, dim3(8, 8, NBATCH), dim3(256), 0, stream, yf, xf, CT, cmax_bits, 0);
  hipLaunchKernelGGL(sinkhorn_kernel, dim3(256), dim3(512), 0, stream, C, CT, u_part, v_part, bar, dist, cmax_bits);
  hipLaunchKernelGGL(finalize_kernel, dim3(1), dim3(64), 0, stream, dist, out);
}

// Round 3
// 1150.004 us; speedup vs baseline: 5.1796x; 2.3201x over previous
//
#include <hip/hip_runtime.h>

#define NBATCH 16
#define NPTS   1024
#define NDIM   1024
#define EPSI   1e-3f
#define NWAVES 8
#define QSCALE 127.5f

typedef __attribute__((ext_vector_type(8))) short short8;
typedef __attribute__((ext_vector_type(4))) float f32x4;

__device__ __forceinline__ unsigned short f2bf(float f) {
  union { float f; unsigned u; } v; v.f = f;
  unsigned r = v.u + 0x7fffu + ((v.u >> 16) & 1u);
  return (unsigned short)(r >> 16);
}

// device-coherent scalar access (per-access sc bits; NO cache-wide fences)
__device__ __forceinline__ float ld_agent(const float* p) {
  return __hip_atomic_load(p, __ATOMIC_RELAXED, __HIP_MEMORY_SCOPE_AGENT);
}
__device__ __forceinline__ void st_agent(float* p, float v) {
  __hip_atomic_store(p, v, __ATOMIC_RELAXED, __HIP_MEMORY_SCOPE_AGENT);
}

// ---------------- normalize: fp32 [B,N,D] -> unit rows, bf16 ----------------
__global__ __launch_bounds__(256) void norm_kernel(const float* __restrict__ x,
                                                   const float* __restrict__ y,
                                                   unsigned short* __restrict__ xf,
                                                   unsigned short* __restrict__ yf) {
  int row = blockIdx.x;
  const float* src; unsigned short* dst;
  if (row < NBATCH * NPTS) { src = x; dst = xf; }
  else { row -= NBATCH * NPTS; src = y; dst = yf; }
  src += (size_t)row * NDIM; dst += (size_t)row * NDIM;
  const int t = threadIdx.x;
  float4 val = ((const float4*)src)[t];
  float ss = val.x*val.x + val.y*val.y + val.z*val.z + val.w*val.w;
  #pragma unroll
  for (int o = 32; o; o >>= 1) ss += __shfl_xor(ss, o, 64);
  __shared__ float wsum[4];
  if ((t & 63) == 0) wsum[t >> 6] = ss;
  __syncthreads();
  float tot = wsum[0] + wsum[1] + wsum[2] + wsum[3];
  float inv = 1.0f / fmaxf(sqrtf(tot), 1e-12f);
  ushort4 o4;
  o4.x = f2bf(val.x * inv); o4.y = f2bf(val.y * inv);
  o4.z = f2bf(val.z * inv); o4.w = f2bf(val.w * inv);
  ((ushort4*)dst)[t] = o4;
}

// ------- batched bf16 GEMM: writes BOTH Cq = q8(1 - A B^T) and its transpose -------
#define GLD_LDS16(g, l) __builtin_amdgcn_global_load_lds( \
    (const __attribute__((address_space(1))) unsigned int*)(g), \
    (__attribute__((address_space(3))) unsigned int*)(l), 16, 0, 0)

__device__ __forceinline__ unsigned char q8(float cv) {
  float t = cv * QSCALE + 0.5f;
  t = fminf(fmaxf(t, 0.f), 255.f);
  return (unsigned char)(int)t;
}

__global__ __launch_bounds__(256) void gemm_cost(const unsigned short* __restrict__ A,
                                                 const unsigned short* __restrict__ B,
                                                 unsigned char* __restrict__ Cq,
                                                 unsigned char* __restrict__ CTq,
                                                 unsigned* __restrict__ cmax_bits) {
  const int b = blockIdx.z;
  const int bm = blockIdx.y * 128, bn = blockIdx.x * 128;
  const int t = threadIdx.x, lane = t & 63, wv = t >> 6;
  const int wm = (wv & 1) * 64, wn = (wv >> 1) * 64;
  __shared__ unsigned short As[128 * 32];
  __shared__ unsigned short Bs[128 * 32];
  f32x4 acc[4][4];
  #pragma unroll
  for (int i = 0; i < 4; ++i)
    #pragma unroll
    for (int j = 0; j < 4; ++j) acc[i][j] = (f32x4){0.f, 0.f, 0.f, 0.f};

  const unsigned short* gA = A + (size_t)b*NPTS*NDIM + (size_t)(bm + (t >> 2))*NDIM + (t & 3)*8;
  const unsigned short* gB = B + (size_t)b*NPTS*NDIM + (size_t)(bn + (t >> 2))*NDIM + (t & 3)*8;
  const int ar = lane & 15, ak = (lane >> 4) * 8;

  for (int k0 = 0; k0 < NDIM; k0 += 32) {
    GLD_LDS16(gA + k0,             As + t*8);
    GLD_LDS16(gA + 64*NDIM + k0,   As + 2048 + t*8);
    GLD_LDS16(gB + k0,             Bs + t*8);
    GLD_LDS16(gB + 64*NDIM + k0,   Bs + 2048 + t*8);
    __syncthreads();
    short8 af[4], bq[4];
    #pragma unroll
    for (int i = 0; i < 4; ++i) af[i] = *(const short8*)(As + (wm + i*16 + ar)*32 + ak);
    #pragma unroll
    for (int j = 0; j < 4; ++j) bq[j] = *(const short8*)(Bs + (wn + j*16 + ar)*32 + ak);
    #pragma unroll
    for (int i = 0; i < 4; ++i)
      #pragma unroll
      for (int j = 0; j < 4; ++j)
        acc[i][j] = __builtin_amdgcn_mfma_f32_16x16x32_bf16(af[i], bq[j], acc[i][j], 0, 0, 0);
    __syncthreads();
  }

  float mx = 0.f;
  const int cr = (lane >> 4) * 4, cc = lane & 15;
  unsigned char* Cb = Cq  + (size_t)b * NPTS * NPTS;
  unsigned char* Tb = CTq + (size_t)b * NPTS * NPTS;
  #pragma unroll
  for (int i = 0; i < 4; ++i) {
    #pragma unroll
    for (int j = 0; j < 4; ++j) {
      const int row0 = bm + wm + i*16 + cr;
      const int col  = bn + wn + j*16 + cc;
      #pragma unroll
      for (int r = 0; r < 4; ++r) {
        float cv = 1.0f - acc[i][j][r];
        mx = fmaxf(mx, cv);
        unsigned char qv = q8(cv);
        Cb[(size_t)(row0 + r) * NPTS + col] = qv;
        Tb[(size_t)col * NPTS + row0 + r]   = qv;
      }
    }
  }
  #pragma unroll
  for (int o = 32; o; o >>= 1) mx = fmaxf(mx, __shfl_xor(mx, o, 64));
  if (lane == 0) atomicMax(cmax_bits, __float_as_uint(mx));
}

// ---------------- persistent Sinkhorn ----------------
// 256 WGs x 512 thr. WG = (b, s); s -> out-slice a (256 outputs), red-chunk j
// (256 reduction idx). Partials plane-major: part[j][1024] per batch -> coalesced.
// Matrix data for phase t+1 prefetched into VGPRs before arriving at barrier t.

__device__ __forceinline__ void batch_barrier(unsigned* bar, unsigned target) {
  __syncthreads();
  if (threadIdx.x == 0) {
    __hip_atomic_fetch_add(bar, 1u, __ATOMIC_RELEASE, __HIP_MEMORY_SCOPE_AGENT);
    while (__hip_atomic_load(bar, __ATOMIC_RELAXED, __HIP_MEMORY_SCOPE_AGENT) < target)
      __builtin_amdgcn_s_sleep(1);
    asm volatile("" ::: "memory");
  }
  __syncthreads();
}

__device__ __forceinline__ void prefetch32(const unsigned char* __restrict__ rowp,
                                           unsigned* r) {
  #pragma unroll
  for (int mi = 0; mi < 32; ++mi)
    r[mi] = *(const unsigned*)(rowp + (size_t)mi * NPTS);
}

// stage g() of 32 source values for this wave (lanes 0..31), AGENT loads first in FIFO
__device__ __forceinline__ void stage_gbuf(const float* __restrict__ srcp,
                                           float* gbuf, int rb, int w, int lane,
                                           float invc2) {
  if (lane < 32) {
    int m = rb + w * 32 + lane;
    float s = ld_agent(&srcp[0*NPTS + m]) + ld_agent(&srcp[1*NPTS + m])
            + ld_agent(&srcp[2*NPTS + m]) + ld_agent(&srcp[3*NPTS + m]);
    gbuf[w * 32 + lane] = 1.0f / (s * invc2 + EPSI);
  }
}

__device__ __forceinline__ float4 compute32(const unsigned* r, const float* gbase) {
  float a0 = 0.f, a1 = 0.f, a2 = 0.f, a3 = 0.f;
  #pragma unroll
  for (int mi = 0; mi < 32; ++mi) {
    unsigned q = r[mi];
    float g = gbase[mi];
    a0 += (float)(q & 0xffu) * g;          // v_cvt_f32_ubyte0
    a1 += (float)((q >> 8) & 0xffu) * g;   // v_cvt_f32_ubyte1
    a2 += (float)((q >> 16) & 0xffu) * g;  // v_cvt_f32_ubyte2
    a3 += (float)(q >> 24) * g;            // v_cvt_f32_ubyte3
  }
  return make_float4(a0, a1, a2, a3);
}

__global__ __launch_bounds__(512) void sinkhorn_kernel(
    const unsigned char* __restrict__ Cq, const unsigned char* __restrict__ CTq,
    float* __restrict__ u_part, float* __restrict__ v_part,
    unsigned* __restrict__ bar, float* __restrict__ dist,
    const unsigned* __restrict__ cmax_bits)
{
  const int wg = blockIdx.x;
  const int b = wg & (NBATCH - 1);
  const int s = wg >> 4;              // 0..15
  const int a = s & 3, j = s >> 2;    // out-slice / red-chunk
  const int ob = a * 256, rb = j * 256;
  const int tid = threadIdx.x, lane = tid & 63, w = tid >> 6;

  __shared__ float gbuf[256];
  __shared__ float red[NWAVES][256];
  __shared__ float dred[NWAVES];

  const float cmax = __uint_as_float(*cmax_bits);
  const float invc2 = 1.0f / (QSCALE * cmax);   // dequant + /cmax folded
  const unsigned char* rowC  = Cq  + (size_t)b*NPTS*NPTS + (size_t)(rb + w*32)*NPTS + ob + lane*4;
  const unsigned char* rowCT = CTq + (size_t)b*NPTS*NPTS + (size_t)(rb + w*32)*NPTS + ob + lane*4;
  float* upb = u_part + b * 4 * NPTS;
  float* vpb = v_part + b * 4 * NPTS;
  unsigned* barb = bar + b * 64;      // 256-byte spacing

  unsigned rA[32], rB[32];

  prefetch32(rowCT, rA);              // phase U0 data, hides behind init barrier
  if (tid < 64) {                     // init: f(v_raw) == 1/N
    float iv = ((float)NPTS - EPSI) * QSCALE * cmax * 0.25f;
    #pragma unroll
    for (int k = 0; k < 4; ++k) st_agent(&vpb[k*NPTS + s*64 + tid], iv);
  }
  unsigned bt = 16;
  batch_barrier(barb, bt); bt += 16;

  for (int it = 0; it < 100; ++it) {
    // ---- phase U: u_raw = CT-cols dot g(v_raw); prefetch C for phase V
    stage_gbuf(vpb, gbuf, rb, w, lane, invc2);
    prefetch32(rowC, rB);
    {
      float4 acc = compute32(rA, &gbuf[w * 32]);
      ((float4*)&red[w][lane * 4])[0] = acc;
      __syncthreads();
      if (tid < 256) {
        float ssum = 0.f;
        #pragma unroll
        for (int ww = 0; ww < NWAVES; ++ww) ssum += red[ww][tid];
        st_agent(&upb[j*NPTS + ob + tid], ssum);
      }
    }
    batch_barrier(barb, bt); bt += 16;

    // ---- phase V: v_raw = C-cols dot g(u_raw); prefetch CT for next U / distance
    stage_gbuf(upb, gbuf, rb, w, lane, invc2);
    prefetch32(rowCT, rA);
    {
      float4 acc = compute32(rB, &gbuf[w * 32]);
      ((float4*)&red[w][lane * 4])[0] = acc;
      __syncthreads();
      if (tid < 256) {
        float ssum = 0.f;
        #pragma unroll
        for (int ww = 0; ww < NWAVES; ++ww) ssum += red[ww][tid];
        st_agent(&vpb[j*NPTS + ob + tid], ssum);
      }
    }
    batch_barrier(barb, bt); bt += 16;
  }

  // ---- distance: sum_n f(u_raw_n) * (C~ g(v))_n   (rA holds CT rows)
  stage_gbuf(vpb, gbuf, rb, w, lane, invc2);
  {
    float4 acc = compute32(rA, &gbuf[w * 32]);
    ((float4*)&red[w][lane * 4])[0] = acc;
    __syncthreads();
    float term = 0.f;
    if (tid < 256) {
      float ssum = 0.f;
      #pragma unroll
      for (int ww = 0; ww < NWAVES; ++ww) ssum += red[ww][tid];
      int n = ob + tid;
      float uq = ld_agent(&upb[0*NPTS + n]) + ld_agent(&upb[1*NPTS + n])
               + ld_agent(&upb[2*NPTS + n]) + ld_agent(&upb[3*NPTS + n]);
      float un = 1.0f / (uq * invc2 + EPSI);
      term = un * ssum * invc2;
    }
    #pragma unroll
    for (int o = 32; o; o >>= 1) term += __shfl_xor(term, o, 64);
    if (lane == 0) dred[w] = term;
    __syncthreads();
    if (tid == 0) {
      float d = 0.f;
      #pragma unroll
      for (int ww = 0; ww < NWAVES; ++ww) d += dred[ww];
      atomicAdd(dist + b, d);
    }
  }
}

__global__ void finalize_kernel(const float* __restrict__ dist, float* __restrict__ out) {
  if (threadIdx.x == 0) {
    float s = 0.f;
    for (int i = 0; i < NBATCH; ++i) s += dist[i];
    out[0] = s * (1.0f / NBATCH);
  }
}

// ---------------- launch ----------------
extern "C" void kernel_launch(void* const* d_in, const int* in_sizes, int n_in,
                              void* d_out, int out_size, void* d_ws, size_t ws_size,
                              hipStream_t stream) {
  (void)in_sizes; (void)n_in; (void)out_size; (void)ws_size;
  const float* x = (const float*)d_in[0];
  const float* y = (const float*)d_in[1];
  float* out = (float*)d_out;
  char* ws = (char*)d_ws;

  unsigned* cmax_bits = (unsigned*)ws;                 // @0
  unsigned* bar       = (unsigned*)(ws + 4096);        // 16 x 256B
  float*    dist      = (float*)(ws + 8192);           // 16 floats
  float*    u_part    = (float*)(ws + 65536);          // 16 x 4 x 1024 f32 = 256 KB
  float*    v_part    = (float*)(ws + 65536 + 262144); // 256 KB
  const size_t MB = 1u << 20;
  unsigned short* xf = (unsigned short*)(ws + 1*MB);   // 32 MB bf16
  unsigned short* yf = (unsigned short*)(ws + 33*MB);  // 32 MB bf16
  unsigned char*  C  = (unsigned char*)(ws + 65*MB);   // 16 MB u8
  unsigned char*  CT = (unsigned char*)(ws + 81*MB);   // 16 MB u8

  hipMemsetAsync(d_ws, 0, 65536, stream);  // cmax / barriers / dist

  hipLaunchKernelGGL(norm_kernel, dim3(2 * NBATCH * NPTS), dim3(256), 0, stream, x, y, xf, yf);
  hipLaunchKernelGGL(gemm_cost, dim3(8, 8, NBATCH), dim3(256), 0, stream, xf, yf, C, CT, cmax_bits);
  hipLaunchKernelGGL(sinkhorn_kernel, dim3(256), dim3(512), 0, stream, C, CT, u_part, v_part, bar, dist, cmax_bits);
  hipLaunchKernelGGL(finalize_kernel, dim3(1), dim3(64), 0, stream, dist, out);
}